// Round 4
// baseline (215.882 us; speedup 1.0000x reference)
//
#include <hip/hip_runtime.h>
#include <stdint.h>

// Problem constants: T_OBS=8, T_PRE=12, B=524288, IN=2, E=16, H=8
#define T_OBS 8
#define T_PRE 12
#define BATCH 524288

#define NLOG2E  (-1.4426950408889634f)   // -log2(e): sigmoid prescale
#define P2LOG2E ( 2.8853900817779268f)   // +2*log2(e): tanh prescale

typedef __fp16 half8  __attribute__((ext_vector_type(8)));
typedef float  floatx16 __attribute__((ext_vector_type(16)));
typedef float  f32x2   __attribute__((ext_vector_type(2)));
typedef unsigned int uint_t;

__device__ __forceinline__ uint_t upk(float a, float b) {
    return __builtin_bit_cast(uint_t, __builtin_amdgcn_cvt_pkrtz(a, b));
}

// ---------------------------------------------------------------------------
// Weight prep -> per-lane MFMA A-fragments for v_mfma_f32_32x32x16_f16.
// A matrix: [M=32 gate rows (i0-7,f0-7,g0-7,o0-7)] x [K=16].
// SYMMETRIC half-lane layout (no cross-lane exchange needed in the step):
//   lower half supplies k0..7  = (x0, x1, h0, h1, h2, h3, 1, 0)
//   upper half supplies k8..15 = (x0, x1, h4, h5, h6, h7, 1, 0)
// A rows: k0,1/k8,9 = folded (W_ih@W_in)*0.5 ; k2..5/k10..13 = W_hh cols ;
//         k6/k14 = folded bias*0.5 ; k7/k15 = 0.
// Sigmoid rows (i,f,o) scaled by -log2e; tanh rows (g) by +2log2e.
// A-fragment layout: lane l holds A[m=l&31][k=(l>>5)*8 + j], j=0..7,
// packed as 4 dwords (f16 pairs). ws layout: uint[phase*256 + lane*4 + r].
// ---------------------------------------------------------------------------
__global__ void prep_weights(const float* __restrict__ W_in,
                             const float* __restrict__ b_in,
                             const float* __restrict__ W_ih_obs,
                             const float* __restrict__ W_hh_obs,
                             const float* __restrict__ b_ih_obs,
                             const float* __restrict__ b_hh_obs,
                             const float* __restrict__ W_ih_pre,
                             const float* __restrict__ W_hh_pre,
                             const float* __restrict__ b_ih_pre,
                             const float* __restrict__ b_hh_pre,
                             uint_t* __restrict__ wsu) {
    int t = threadIdx.x;            // 0..127: phase*64 + lane
    int phase = t >> 6;
    int l = t & 63;
    int m = l & 31;                 // gate row
    int kh = l >> 5;                // k-half: 0 -> k0..7, 1 -> k8..15
    const float* W_ih = phase ? W_ih_pre : W_ih_obs;
    const float* W_hh = phase ? W_hh_pre : W_hh_obs;
    const float* b_ih = phase ? b_ih_pre : b_ih_obs;
    const float* b_hh = phase ? b_hh_pre : b_hh_obs;

    float wx0 = 0.f, wx1 = 0.f;
    float bb = b_ih[m] + b_hh[m];
    #pragma unroll
    for (int e = 0; e < 16; e++) {
        float wie = W_ih[m * 16 + e];
        wx0 += wie * W_in[e * 2 + 0];
        wx1 += wie * W_in[e * 2 + 1];
        bb  += wie * b_in[e];
    }
    float s = (m >= 16 && m < 24) ? P2LOG2E : NLOG2E;

    float af[16];
    af[0] = wx0 * s * 0.5f;          // x slots appear in BOTH k-halves:
    af[1] = wx1 * s * 0.5f;          // half weight each (exact in f16)
    #pragma unroll
    for (int j = 0; j < 4; j++) af[2 + j] = W_hh[m * 8 + j] * s;
    af[6] = bb * s * 0.5f;
    af[7] = 0.f;
    af[8] = af[0];
    af[9] = af[1];
    #pragma unroll
    for (int j = 0; j < 4; j++) af[10 + j] = W_hh[m * 8 + 4 + j] * s;
    af[14] = af[6];
    af[15] = 0.f;

    #pragma unroll
    for (int r = 0; r < 4; r++)
        wsu[phase * 256 + l * 4 + r] = upk(af[kh * 8 + 2 * r], af[kh * 8 + 2 * r + 1]);
}

// ---------------------------------------------------------------------------
// Activation math on unit-PAIRS as <2 x float> so clang lowers the full-rate
// ops to v_pk_{add,mul,fma}_f32. Trans ops per unit: 5 exp2 + 1 shared rcp
// (paired Montgomery inversion: rcp(d0*d1) then two muls recovers 1/d0, 1/d1
// at ~2ulp — far below the f16-weight noise floor).
//   cn = [c*(1+ei)(1+eg) + (eg-1)(1+ef)] / [(1+ei)(1+ef)(1+eg)]
//   h  = (ec-1) / [(1+eo)(1+ec)],  ec = exp2(2*log2e*cn)
// Trans per tile-step: 16 gate exp2 + 4 tanh exp2 + 4 rcp = 24 (was 28).
// ---------------------------------------------------------------------------
__device__ __forceinline__ f32x2 exp2v(f32x2 a) {
    f32x2 r;
    r.x = __builtin_amdgcn_exp2f(a.x);
    r.y = __builtin_amdgcn_exp2f(a.y);
    return r;
}
// 1/d.x, 1/d.y with a single v_rcp via batch inversion.
__device__ __forceinline__ f32x2 rcp_pair(f32x2 d) {
    float r = __builtin_amdgcn_rcpf(d.x * d.y);
    f32x2 o;
    o.x = r * d.y;
    o.y = r * d.x;
    return o;
}

__device__ __forceinline__ void act_pair(f32x2 gi, f32x2 gf, f32x2 gg, f32x2 go,
                                         f32x2& c, f32x2& h) {
    f32x2 ei = exp2v(gi);             // e^{-i}
    f32x2 ef = exp2v(gf);             // e^{-f}
    f32x2 eg = exp2v(gg);             // e^{2g}
    f32x2 eo = exp2v(go);             // e^{-o}
    f32x2 ai = ei + 1.f;
    f32x2 af = ef + 1.f;
    f32x2 ag = eg + 1.f;
    f32x2 gm = eg - 1.f;
    f32x2 p  = ai * ag;
    f32x2 num = c * p + gm * af;
    f32x2 cn  = num * rcp_pair(p * af);
    c = cn;
    f32x2 ec = exp2v(P2LOG2E * cn);   // e^{2*cn}
    h = (ec - 1.f) * rcp_pair((eo + 1.f) * (ec + 1.f));
}

// Per-wave-tile LSTM state: 32 batch cols, this lane owns 4 units of col n.
struct Tile {
    f32x2 c01, c23;   // cell state, units (0,1)/(2,3) of this lane's half
    f32x2 h01, h23;   // hidden state
    uint_t pk0, pk1;  // h packed to f16 pairs for the next B fragment
};

// One LSTM step for one 32-batch tile via a single 32x32x16 MFMA.
// B fragment is identical in shape for both lane halves (no shfl/cndmask):
//   bu = { (x0,x1), (hA,hB), (hC,hD), (1.0, 0) }
__device__ __forceinline__ void lstm_step(half8 A, uint_t xpk, Tile& T,
                                          const floatx16& zacc) {
    uint4 bu;
    bu.x = xpk;               // k0,1  | k8,9   : x0, x1
    bu.y = T.pk0;             // k2,3  | k10,11 : h0,h1 | h4,h5
    bu.z = T.pk1;             // k4,5  | k12,13 : h2,h3 | h6,h7
    bu.w = 0x00003C00u;       // k6,7  | k14,15 : 1.0, 0 (bias slot)
    half8 B = __builtin_bit_cast(half8, bu);

    floatx16 d = __builtin_amdgcn_mfma_f32_32x32x16_f16(A, B, zacc, 0, 0, 0);

    // D rows for this lane: reg j -> i-unit j, 4+j -> f, 8+j -> g, 12+j -> o
    f32x2 gi, gf, gg, go;
    gi.x = d[0];  gi.y = d[1];
    gf.x = d[4];  gf.y = d[5];
    gg.x = d[8];  gg.y = d[9];
    go.x = d[12]; go.y = d[13];
    act_pair(gi, gf, gg, go, T.c01, T.h01);
    gi.x = d[2];  gi.y = d[3];
    gf.x = d[6];  gf.y = d[7];
    gg.x = d[10]; gg.y = d[11];
    go.x = d[14]; go.y = d[15];
    act_pair(gi, gf, gg, go, T.c23, T.h23);

    T.pk0 = upk(T.h01.x, T.h01.y);
    T.pk1 = upk(T.h23.x, T.h23.y);
}

// ---------------------------------------------------------------------------
// 2 waves/block x 2 tiles/wave: keeps R2's dual dependency-chain ILP but
// doubles the workgroup count back to 4096 (R2's 2048-block config dropped
// OccupancyPercent to 45% and gave back part of the ILP win). Block covers
// 2*2*32 = 128 batch elements.
// ---------------------------------------------------------------------------
__global__ __launch_bounds__(128, 8)
void lstm_encoder(const float2* __restrict__ obs,
                  const float2* __restrict__ pre,
                  const float4* __restrict__ h0,
                  const float4* __restrict__ c0,
                  const float4* __restrict__ c0p,
                  const uint4* __restrict__ wf,
                  float* __restrict__ out) {
    const int tid  = threadIdx.x;
    const int lane = tid & 63;
    const int wv   = tid >> 6;              // wave in block: 0..1
    const int n    = lane & 31;             // batch col within tile
    const int half = lane >> 5;             // 0: units 0-3, 1: units 4-7
    const size_t nbA = (size_t)blockIdx.x * 128 + wv * 64 + n;
    const size_t nbB = nbA + 32;

    half8 Aobs = __builtin_bit_cast(half8, wf[lane]);
    half8 Apre = __builtin_bit_cast(half8, wf[64 + lane]);

    floatx16 zacc;
    #pragma unroll
    for (int i = 0; i < 16; i++) zacc[i] = 0.f;

    Tile TA, TB;
    {
        float4 hvA = h0[nbA * 2 + half];
        float4 cvA = c0[nbA * 2 + half];
        float4 hvB = h0[nbB * 2 + half];
        float4 cvB = c0[nbB * 2 + half];
        TA.c01.x = cvA.x; TA.c01.y = cvA.y; TA.c23.x = cvA.z; TA.c23.y = cvA.w;
        TB.c01.x = cvB.x; TB.c01.y = cvB.y; TB.c23.x = cvB.z; TB.c23.y = cvB.w;
        TA.pk0 = upk(hvA.x, hvA.y); TA.pk1 = upk(hvA.z, hvA.w);
        TB.pk0 = upk(hvB.x, hvB.y); TB.pk1 = upk(hvB.z, hvB.w);
    }
    // hoist c0_pre loads: latency hides under the whole obs phase
    float4 cvA2 = c0p[nbA * 2 + half];
    float4 cvB2 = c0p[nbB * 2 + half];

    // 1-deep x prefetch: next step's loads issue before this step's math.
    float2 xvA = obs[nbA];
    float2 xvB = obs[nbB];
    #pragma unroll 1
    for (int t = 0; t < T_OBS - 1; t++) {
        float2 xnA = obs[(size_t)(t + 1) * BATCH + nbA];
        float2 xnB = obs[(size_t)(t + 1) * BATCH + nbB];
        lstm_step(Aobs, upk(xvA.x, xvA.y), TA, zacc);
        lstm_step(Aobs, upk(xvB.x, xvB.y), TB, zacc);
        xvA = xnA; xvB = xnB;
    }
    {   // last obs step; prefetch first pre step
        float2 xnA = pre[nbA];
        float2 xnB = pre[nbB];
        lstm_step(Aobs, upk(xvA.x, xvA.y), TA, zacc);
        lstm_step(Aobs, upk(xvB.x, xvB.y), TB, zacc);
        xvA = xnA; xvB = xnB;
    }

    // c_out (transpose-then-reshape): out[u*B + b] = h[b][u]
    out[(size_t)(half * 4 + 0) * BATCH + nbA] = TA.h01.x;
    out[(size_t)(half * 4 + 1) * BATCH + nbA] = TA.h01.y;
    out[(size_t)(half * 4 + 2) * BATCH + nbA] = TA.h23.x;
    out[(size_t)(half * 4 + 3) * BATCH + nbA] = TA.h23.y;
    out[(size_t)(half * 4 + 0) * BATCH + nbB] = TB.h01.x;
    out[(size_t)(half * 4 + 1) * BATCH + nbB] = TB.h01.y;
    out[(size_t)(half * 4 + 2) * BATCH + nbB] = TB.h23.x;
    out[(size_t)(half * 4 + 3) * BATCH + nbB] = TB.h23.y;

    // pre phase: h carries over, c re-initialized
    TA.c01.x = cvA2.x; TA.c01.y = cvA2.y; TA.c23.x = cvA2.z; TA.c23.y = cvA2.w;
    TB.c01.x = cvB2.x; TB.c01.y = cvB2.y; TB.c23.x = cvB2.z; TB.c23.y = cvB2.w;

    #pragma unroll 1
    for (int t = 0; t < T_PRE - 1; t++) {
        float2 xnA = pre[(size_t)(t + 1) * BATCH + nbA];
        float2 xnB = pre[(size_t)(t + 1) * BATCH + nbB];
        lstm_step(Apre, upk(xvA.x, xvA.y), TA, zacc);
        lstm_step(Apre, upk(xvB.x, xvB.y), TB, zacc);
        xvA = xnA; xvB = xnB;
    }
    lstm_step(Apre, upk(xvA.x, xvA.y), TA, zacc);
    lstm_step(Apre, upk(xvB.x, xvB.y), TB, zacc);

    out[(size_t)(8 + half * 4 + 0) * BATCH + nbA] = TA.h01.x;
    out[(size_t)(8 + half * 4 + 1) * BATCH + nbA] = TA.h01.y;
    out[(size_t)(8 + half * 4 + 2) * BATCH + nbA] = TA.h23.x;
    out[(size_t)(8 + half * 4 + 3) * BATCH + nbA] = TA.h23.y;
    out[(size_t)(8 + half * 4 + 0) * BATCH + nbB] = TB.h01.x;
    out[(size_t)(8 + half * 4 + 1) * BATCH + nbB] = TB.h01.y;
    out[(size_t)(8 + half * 4 + 2) * BATCH + nbB] = TB.h23.x;
    out[(size_t)(8 + half * 4 + 3) * BATCH + nbB] = TB.h23.y;
}

extern "C" void kernel_launch(void* const* d_in, const int* in_sizes, int n_in,
                              void* d_out, int out_size, void* d_ws, size_t ws_size,
                              hipStream_t stream) {
    prep_weights<<<1, 128, 0, stream>>>(
        (const float*)d_in[5],  (const float*)d_in[6],
        (const float*)d_in[7],  (const float*)d_in[8],
        (const float*)d_in[9],  (const float*)d_in[10],
        (const float*)d_in[11], (const float*)d_in[12],
        (const float*)d_in[13], (const float*)d_in[14],
        (uint_t*)d_ws);

    lstm_encoder<<<BATCH / 128, 128, 0, stream>>>(
        (const float2*)d_in[0], (const float2*)d_in[1],
        (const float4*)d_in[2], (const float4*)d_in[3], (const float4*)d_in[4],
        (const uint4*)d_ws, (float*)d_out);
}

// Round 5
// 213.699 us; speedup vs baseline: 1.0102x; 1.0102x over previous
//
#include <hip/hip_runtime.h>
#include <stdint.h>

// Problem constants: T_OBS=8, T_PRE=12, B=524288, IN=2, E=16, H=8
#define T_OBS 8
#define T_PRE 12
#define BATCH 524288

#define NLOG2E  (-1.4426950408889634f)   // -log2(e): sigmoid prescale
#define P2LOG2E ( 2.8853900817779268f)   // +2*log2(e): tanh prescale

typedef __fp16 half8  __attribute__((ext_vector_type(8)));
typedef float  floatx16 __attribute__((ext_vector_type(16)));
typedef float  f32x2   __attribute__((ext_vector_type(2)));
typedef unsigned int uint_t;

__device__ __forceinline__ uint_t upk(float a, float b) {
    return __builtin_bit_cast(uint_t, __builtin_amdgcn_cvt_pkrtz(a, b));
}

// ---------------------------------------------------------------------------
// Weight prep -> per-lane MFMA A-fragments for v_mfma_f32_32x32x16_f16.
// A matrix: [M=32 gate rows (i0-7,f0-7,g0-7,o0-7)] x [K=16].
// SYMMETRIC half-lane layout (no cross-lane exchange needed in the step):
//   lower half supplies k0..7  = (x0, x1, h0, h1, h2, h3, 1, 0)
//   upper half supplies k8..15 = (x0, x1, h4, h5, h6, h7, 1, 0)
// A rows: k0,1/k8,9 = folded (W_ih@W_in)*0.5 ; k2..5/k10..13 = W_hh cols ;
//         k6/k14 = folded bias*0.5 ; k7/k15 = 0.
// Sigmoid rows (i,f,o) scaled by -log2e; tanh rows (g) by +2log2e.
// A-fragment layout: lane l holds A[m=l&31][k=(l>>5)*8 + j], j=0..7,
// packed as 4 dwords (f16 pairs). ws layout: uint[phase*256 + lane*4 + r].
// ---------------------------------------------------------------------------
__global__ void prep_weights(const float* __restrict__ W_in,
                             const float* __restrict__ b_in,
                             const float* __restrict__ W_ih_obs,
                             const float* __restrict__ W_hh_obs,
                             const float* __restrict__ b_ih_obs,
                             const float* __restrict__ b_hh_obs,
                             const float* __restrict__ W_ih_pre,
                             const float* __restrict__ W_hh_pre,
                             const float* __restrict__ b_ih_pre,
                             const float* __restrict__ b_hh_pre,
                             uint_t* __restrict__ wsu) {
    int t = threadIdx.x;            // 0..127: phase*64 + lane
    int phase = t >> 6;
    int l = t & 63;
    int m = l & 31;                 // gate row
    int kh = l >> 5;                // k-half: 0 -> k0..7, 1 -> k8..15
    const float* W_ih = phase ? W_ih_pre : W_ih_obs;
    const float* W_hh = phase ? W_hh_pre : W_hh_obs;
    const float* b_ih = phase ? b_ih_pre : b_ih_obs;
    const float* b_hh = phase ? b_hh_pre : b_hh_obs;

    float wx0 = 0.f, wx1 = 0.f;
    float bb = b_ih[m] + b_hh[m];
    #pragma unroll
    for (int e = 0; e < 16; e++) {
        float wie = W_ih[m * 16 + e];
        wx0 += wie * W_in[e * 2 + 0];
        wx1 += wie * W_in[e * 2 + 1];
        bb  += wie * b_in[e];
    }
    float s = (m >= 16 && m < 24) ? P2LOG2E : NLOG2E;

    float af[16];
    af[0] = wx0 * s * 0.5f;          // x slots appear in BOTH k-halves:
    af[1] = wx1 * s * 0.5f;          // half weight each (exact in f16)
    #pragma unroll
    for (int j = 0; j < 4; j++) af[2 + j] = W_hh[m * 8 + j] * s;
    af[6] = bb * s * 0.5f;
    af[7] = 0.f;
    af[8] = af[0];
    af[9] = af[1];
    #pragma unroll
    for (int j = 0; j < 4; j++) af[10 + j] = W_hh[m * 8 + 4 + j] * s;
    af[14] = af[6];
    af[15] = 0.f;

    #pragma unroll
    for (int r = 0; r < 4; r++)
        wsu[phase * 256 + l * 4 + r] = upk(af[kh * 8 + 2 * r], af[kh * 8 + 2 * r + 1]);
}

// ---------------------------------------------------------------------------
// Activation math on unit-PAIRS as <2 x float> so clang lowers the full-rate
// ops to v_pk_{add,mul,fma}_f32. Trans ops per unit: 5 exp2 + 1 shared rcp
// (paired Montgomery inversion: rcp(d0*d1) then two muls recovers 1/d0, 1/d1
// at ~2ulp — far below the f16-weight noise floor).
//   cn = [c*(1+ei)(1+eg) + (eg-1)(1+ef)] / [(1+ei)(1+ef)(1+eg)]
//   h  = (ec-1) / [(1+eo)(1+ec)],  ec = exp2(2*log2e*cn)
// Trans per tile-step: 16 gate exp2 + 4 tanh exp2 + 4 rcp = 24.
// ---------------------------------------------------------------------------
__device__ __forceinline__ f32x2 exp2v(f32x2 a) {
    f32x2 r;
    r.x = __builtin_amdgcn_exp2f(a.x);
    r.y = __builtin_amdgcn_exp2f(a.y);
    return r;
}
// 1/d.x, 1/d.y with a single v_rcp via batch inversion.
__device__ __forceinline__ f32x2 rcp_pair(f32x2 d) {
    float r = __builtin_amdgcn_rcpf(d.x * d.y);
    f32x2 o;
    o.x = r * d.y;
    o.y = r * d.x;
    return o;
}

__device__ __forceinline__ void act_pair(f32x2 gi, f32x2 gf, f32x2 gg, f32x2 go,
                                         f32x2& c, f32x2& h) {
    f32x2 ei = exp2v(gi);             // e^{-i}
    f32x2 ef = exp2v(gf);             // e^{-f}
    f32x2 eg = exp2v(gg);             // e^{2g}
    f32x2 eo = exp2v(go);             // e^{-o}
    f32x2 ai = ei + 1.f;
    f32x2 af = ef + 1.f;
    f32x2 ag = eg + 1.f;
    f32x2 gm = eg - 1.f;
    f32x2 p  = ai * ag;
    f32x2 num = c * p + gm * af;
    f32x2 cn  = num * rcp_pair(p * af);
    c = cn;
    f32x2 ec = exp2v(P2LOG2E * cn);   // e^{2*cn}
    h = (ec - 1.f) * rcp_pair((eo + 1.f) * (ec + 1.f));
}

// Per-wave-tile LSTM state: 32 batch cols, this lane owns 4 units of col n.
struct Tile {
    f32x2 c01, c23;   // cell state, units (0,1)/(2,3) of this lane's half
    f32x2 h01, h23;   // hidden state
    uint_t pk0, pk1;  // h packed to f16 pairs for the next B fragment
};

// One LSTM step for one 32-batch tile via a single 32x32x16 MFMA.
// B fragment is identical in shape for both lane halves (no shfl/cndmask):
//   bu = { (x0,x1), (hA,hB), (hC,hD), (1.0, 0) }
__device__ __forceinline__ void lstm_step(half8 A, uint_t xpk, Tile& T,
                                          const floatx16& zacc) {
    uint4 bu;
    bu.x = xpk;               // k0,1  | k8,9   : x0, x1
    bu.y = T.pk0;             // k2,3  | k10,11 : h0,h1 | h4,h5
    bu.z = T.pk1;             // k4,5  | k12,13 : h2,h3 | h6,h7
    bu.w = 0x00003C00u;       // k6,7  | k14,15 : 1.0, 0 (bias slot)
    half8 B = __builtin_bit_cast(half8, bu);

    floatx16 d = __builtin_amdgcn_mfma_f32_32x32x16_f16(A, B, zacc, 0, 0, 0);

    // D rows for this lane: reg j -> i-unit j, 4+j -> f, 8+j -> g, 12+j -> o
    f32x2 gi, gf, gg, go;
    gi.x = d[0];  gi.y = d[1];
    gf.x = d[4];  gf.y = d[5];
    gg.x = d[8];  gg.y = d[9];
    go.x = d[12]; go.y = d[13];
    act_pair(gi, gf, gg, go, T.c01, T.h01);
    gi.x = d[2];  gi.y = d[3];
    gf.x = d[6];  gf.y = d[7];
    gg.x = d[10]; gg.y = d[11];
    go.x = d[14]; go.y = d[15];
    act_pair(gi, gf, gg, go, T.c23, T.h23);

    T.pk0 = upk(T.h01.x, T.h01.y);
    T.pk1 = upk(T.h23.x, T.h23.y);
}

// ---------------------------------------------------------------------------
// FOUR 32-batch tiles per wave (ILP x4), 256-thread blocks, bounds (256,4):
// R2 vs R4 A/B showed per-wave chain count + VGPR headroom beats nominal
// occupancy (R4's reg-squeezed 2-chain config regressed). 4 independent
// MFMA->act chains fill the trans-latency stalls that leave ~40% of issue
// slots idle. Grid = BATCH/512 = 1024 = exactly 4 WGs/CU.
// ---------------------------------------------------------------------------
#define STEP4(AF)                                              \
    do {                                                       \
        lstm_step(AF, upk(xvA.x, xvA.y), TA, zacc);            \
        lstm_step(AF, upk(xvB.x, xvB.y), TB, zacc);            \
        lstm_step(AF, upk(xvC.x, xvC.y), TC, zacc);            \
        lstm_step(AF, upk(xvD.x, xvD.y), TD, zacc);            \
    } while (0)

#define PREFETCH(src, idx)                                     \
    do {                                                       \
        xnA = src[(idx) * (size_t)BATCH + nbA];                \
        xnB = src[(idx) * (size_t)BATCH + nbB];                \
        xnC = src[(idx) * (size_t)BATCH + nbC];                \
        xnD = src[(idx) * (size_t)BATCH + nbD];                \
    } while (0)

#define ROLL() do { xvA = xnA; xvB = xnB; xvC = xnC; xvD = xnD; } while (0)

#define STORE_H(base)                                                        \
    do {                                                                     \
        out[(size_t)((base) + half * 4 + 0) * BATCH + nbA] = TA.h01.x;       \
        out[(size_t)((base) + half * 4 + 1) * BATCH + nbA] = TA.h01.y;       \
        out[(size_t)((base) + half * 4 + 2) * BATCH + nbA] = TA.h23.x;       \
        out[(size_t)((base) + half * 4 + 3) * BATCH + nbA] = TA.h23.y;       \
        out[(size_t)((base) + half * 4 + 0) * BATCH + nbB] = TB.h01.x;       \
        out[(size_t)((base) + half * 4 + 1) * BATCH + nbB] = TB.h01.y;       \
        out[(size_t)((base) + half * 4 + 2) * BATCH + nbB] = TB.h23.x;       \
        out[(size_t)((base) + half * 4 + 3) * BATCH + nbB] = TB.h23.y;       \
        out[(size_t)((base) + half * 4 + 0) * BATCH + nbC] = TC.h01.x;       \
        out[(size_t)((base) + half * 4 + 1) * BATCH + nbC] = TC.h01.y;       \
        out[(size_t)((base) + half * 4 + 2) * BATCH + nbC] = TC.h23.x;       \
        out[(size_t)((base) + half * 4 + 3) * BATCH + nbC] = TC.h23.y;       \
        out[(size_t)((base) + half * 4 + 0) * BATCH + nbD] = TD.h01.x;       \
        out[(size_t)((base) + half * 4 + 1) * BATCH + nbD] = TD.h01.y;       \
        out[(size_t)((base) + half * 4 + 2) * BATCH + nbD] = TD.h23.x;       \
        out[(size_t)((base) + half * 4 + 3) * BATCH + nbD] = TD.h23.y;       \
    } while (0)

__global__ __launch_bounds__(256, 4)
void lstm_encoder(const float2* __restrict__ obs,
                  const float2* __restrict__ pre,
                  const float4* __restrict__ h0,
                  const float4* __restrict__ c0,
                  const float4* __restrict__ c0p,
                  const uint4* __restrict__ wf,
                  float* __restrict__ out) {
    const int tid  = threadIdx.x;
    const int lane = tid & 63;
    const int wv   = tid >> 6;              // wave in block: 0..3
    const int n    = lane & 31;             // batch col within tile
    const int half = lane >> 5;             // 0: units 0-3, 1: units 4-7
    const size_t nbA = (size_t)blockIdx.x * 512 + wv * 128 + n;
    const size_t nbB = nbA + 32;
    const size_t nbC = nbA + 64;
    const size_t nbD = nbA + 96;

    half8 Aobs = __builtin_bit_cast(half8, wf[lane]);
    half8 Apre = __builtin_bit_cast(half8, wf[64 + lane]);

    floatx16 zacc;
    #pragma unroll
    for (int i = 0; i < 16; i++) zacc[i] = 0.f;

    Tile TA, TB, TC, TD;
    {
        float4 hvA = h0[nbA * 2 + half];
        float4 cvA = c0[nbA * 2 + half];
        float4 hvB = h0[nbB * 2 + half];
        float4 cvB = c0[nbB * 2 + half];
        float4 hvC = h0[nbC * 2 + half];
        float4 cvC = c0[nbC * 2 + half];
        float4 hvD = h0[nbD * 2 + half];
        float4 cvD = c0[nbD * 2 + half];
        TA.c01.x = cvA.x; TA.c01.y = cvA.y; TA.c23.x = cvA.z; TA.c23.y = cvA.w;
        TB.c01.x = cvB.x; TB.c01.y = cvB.y; TB.c23.x = cvB.z; TB.c23.y = cvB.w;
        TC.c01.x = cvC.x; TC.c01.y = cvC.y; TC.c23.x = cvC.z; TC.c23.y = cvC.w;
        TD.c01.x = cvD.x; TD.c01.y = cvD.y; TD.c23.x = cvD.z; TD.c23.y = cvD.w;
        TA.pk0 = upk(hvA.x, hvA.y); TA.pk1 = upk(hvA.z, hvA.w);
        TB.pk0 = upk(hvB.x, hvB.y); TB.pk1 = upk(hvB.z, hvB.w);
        TC.pk0 = upk(hvC.x, hvC.y); TC.pk1 = upk(hvC.z, hvC.w);
        TD.pk0 = upk(hvD.x, hvD.y); TD.pk1 = upk(hvD.z, hvD.w);
    }

    float2 xvA, xvB, xvC, xvD;
    float2 xnA, xnB, xnC, xnD;
    xvA = obs[nbA]; xvB = obs[nbB]; xvC = obs[nbC]; xvD = obs[nbD];

    #pragma unroll 1
    for (int t = 0; t < T_OBS - 1; t++) {
        PREFETCH(obs, (size_t)(t + 1));
        STEP4(Aobs);
        ROLL();
    }
    {   // last obs step; prefetch first pre step
        PREFETCH(pre, (size_t)0);
        STEP4(Aobs);
        ROLL();
    }

    // c_out (transpose-then-reshape): out[u*B + b] = h[b][u]
    STORE_H(0);

    // pre phase: h carries over, c re-initialized
    {
        float4 cvA2 = c0p[nbA * 2 + half];
        float4 cvB2 = c0p[nbB * 2 + half];
        float4 cvC2 = c0p[nbC * 2 + half];
        float4 cvD2 = c0p[nbD * 2 + half];
        TA.c01.x = cvA2.x; TA.c01.y = cvA2.y; TA.c23.x = cvA2.z; TA.c23.y = cvA2.w;
        TB.c01.x = cvB2.x; TB.c01.y = cvB2.y; TB.c23.x = cvB2.z; TB.c23.y = cvB2.w;
        TC.c01.x = cvC2.x; TC.c01.y = cvC2.y; TC.c23.x = cvC2.z; TC.c23.y = cvC2.w;
        TD.c01.x = cvD2.x; TD.c01.y = cvD2.y; TD.c23.x = cvD2.z; TD.c23.y = cvD2.w;
    }

    #pragma unroll 1
    for (int t = 0; t < T_PRE - 1; t++) {
        PREFETCH(pre, (size_t)(t + 1));
        STEP4(Apre);
        ROLL();
    }
    STEP4(Apre);

    STORE_H(8);
}

extern "C" void kernel_launch(void* const* d_in, const int* in_sizes, int n_in,
                              void* d_out, int out_size, void* d_ws, size_t ws_size,
                              hipStream_t stream) {
    prep_weights<<<1, 128, 0, stream>>>(
        (const float*)d_in[5],  (const float*)d_in[6],
        (const float*)d_in[7],  (const float*)d_in[8],
        (const float*)d_in[9],  (const float*)d_in[10],
        (const float*)d_in[11], (const float*)d_in[12],
        (const float*)d_in[13], (const float*)d_in[14],
        (uint_t*)d_ws);

    lstm_encoder<<<BATCH / 512, 256, 0, stream>>>(
        (const float2*)d_in[0], (const float2*)d_in[1],
        (const float4*)d_in[2], (const float4*)d_in[3], (const float4*)d_in[4],
        (const uint4*)d_ws, (float*)d_out);
}

// Round 6
// 210.799 us; speedup vs baseline: 1.0241x; 1.0138x over previous
//
#include <hip/hip_runtime.h>
#include <stdint.h>

// Problem constants: T_OBS=8, T_PRE=12, B=524288, IN=2, E=16, H=8
#define T_OBS 8
#define T_PRE 12
#define BATCH 524288

#define NLOG2E  (-1.4426950408889634f)   // -log2(e): sigmoid prescale
#define P2LOG2E ( 2.8853900817779268f)   // +2*log2(e): tanh prescale

typedef __fp16 half8  __attribute__((ext_vector_type(8)));
typedef float  floatx16 __attribute__((ext_vector_type(16)));
typedef float  f32x2   __attribute__((ext_vector_type(2)));
typedef unsigned int uint_t;

__device__ __forceinline__ uint_t upk(float a, float b) {
    return __builtin_bit_cast(uint_t, __builtin_amdgcn_cvt_pkrtz(a, b));
}

// ---------------------------------------------------------------------------
// Weight prep -> per-lane MFMA A-fragments for v_mfma_f32_32x32x16_f16.
// A matrix: [M=32 gate rows (i0-7,f0-7,g0-7,o0-7)] x [K=16].
// SYMMETRIC half-lane layout (no cross-lane exchange needed in the step):
//   lower half supplies k0..7  = (x0, x1, h0, h1, h2, h3, 1, 0)
//   upper half supplies k8..15 = (x0, x1, h4, h5, h6, h7, 1, 0)
// A rows: k0,1/k8,9 = folded (W_ih@W_in)*0.5 ; k2..5/k10..13 = W_hh cols ;
//         k6/k14 = folded bias*0.5 ; k7/k15 = 0.
// Sigmoid rows (i,f,o) scaled by -log2e; tanh rows (g) by +2log2e.
// A-fragment layout: lane l holds A[m=l&31][k=(l>>5)*8 + j], j=0..7,
// packed as 4 dwords (f16 pairs). ws layout: uint[phase*256 + lane*4 + r].
// ---------------------------------------------------------------------------
__global__ void prep_weights(const float* __restrict__ W_in,
                             const float* __restrict__ b_in,
                             const float* __restrict__ W_ih_obs,
                             const float* __restrict__ W_hh_obs,
                             const float* __restrict__ b_ih_obs,
                             const float* __restrict__ b_hh_obs,
                             const float* __restrict__ W_ih_pre,
                             const float* __restrict__ W_hh_pre,
                             const float* __restrict__ b_ih_pre,
                             const float* __restrict__ b_hh_pre,
                             uint_t* __restrict__ wsu) {
    int t = threadIdx.x;            // 0..127: phase*64 + lane
    int phase = t >> 6;
    int l = t & 63;
    int m = l & 31;                 // gate row
    int kh = l >> 5;                // k-half: 0 -> k0..7, 1 -> k8..15
    const float* W_ih = phase ? W_ih_pre : W_ih_obs;
    const float* W_hh = phase ? W_hh_pre : W_hh_obs;
    const float* b_ih = phase ? b_ih_pre : b_ih_obs;
    const float* b_hh = phase ? b_hh_pre : b_hh_obs;

    float wx0 = 0.f, wx1 = 0.f;
    float bb = b_ih[m] + b_hh[m];
    #pragma unroll
    for (int e = 0; e < 16; e++) {
        float wie = W_ih[m * 16 + e];
        wx0 += wie * W_in[e * 2 + 0];
        wx1 += wie * W_in[e * 2 + 1];
        bb  += wie * b_in[e];
    }
    float s = (m >= 16 && m < 24) ? P2LOG2E : NLOG2E;

    float af[16];
    af[0] = wx0 * s * 0.5f;          // x slots appear in BOTH k-halves:
    af[1] = wx1 * s * 0.5f;          // half weight each (exact in f16)
    #pragma unroll
    for (int j = 0; j < 4; j++) af[2 + j] = W_hh[m * 8 + j] * s;
    af[6] = bb * s * 0.5f;
    af[7] = 0.f;
    af[8] = af[0];
    af[9] = af[1];
    #pragma unroll
    for (int j = 0; j < 4; j++) af[10 + j] = W_hh[m * 8 + 4 + j] * s;
    af[14] = af[6];
    af[15] = 0.f;

    #pragma unroll
    for (int r = 0; r < 4; r++)
        wsu[phase * 256 + l * 4 + r] = upk(af[kh * 8 + 2 * r], af[kh * 8 + 2 * r + 1]);
}

// ---------------------------------------------------------------------------
// Activation math on unit-PAIRS as <2 x float> so clang lowers the full-rate
// ops to v_pk_{add,mul,fma}_f32. Trans ops per unit: 5 exp2 + 1 shared rcp
// (paired Montgomery inversion: rcp(d0*d1) then two muls recovers 1/d0, 1/d1
// at ~2ulp — far below the f16-weight noise floor).
//   cn = [c*(1+ei)(1+eg) + (eg-1)(1+ef)] / [(1+ei)(1+ef)(1+eg)]
//   h  = (ec-1) / [(1+eo)(1+ec)],  ec = exp2(2*log2e*cn)
// Trans per tile-step: 16 gate exp2 + 4 tanh exp2 + 4 rcp = 24.
// ---------------------------------------------------------------------------
__device__ __forceinline__ f32x2 exp2v(f32x2 a) {
    f32x2 r;
    r.x = __builtin_amdgcn_exp2f(a.x);
    r.y = __builtin_amdgcn_exp2f(a.y);
    return r;
}
// 1/d.x, 1/d.y with a single v_rcp via batch inversion.
__device__ __forceinline__ f32x2 rcp_pair(f32x2 d) {
    float r = __builtin_amdgcn_rcpf(d.x * d.y);
    f32x2 o;
    o.x = r * d.y;
    o.y = r * d.x;
    return o;
}

__device__ __forceinline__ void act_pair(f32x2 gi, f32x2 gf, f32x2 gg, f32x2 go,
                                         f32x2& c, f32x2& h) {
    f32x2 ei = exp2v(gi);             // e^{-i}
    f32x2 ef = exp2v(gf);             // e^{-f}
    f32x2 eg = exp2v(gg);             // e^{2g}
    f32x2 eo = exp2v(go);             // e^{-o}
    f32x2 ai = ei + 1.f;
    f32x2 af = ef + 1.f;
    f32x2 ag = eg + 1.f;
    f32x2 gm = eg - 1.f;
    f32x2 p  = ai * ag;
    f32x2 num = c * p + gm * af;
    f32x2 cn  = num * rcp_pair(p * af);
    c = cn;
    f32x2 ec = exp2v(P2LOG2E * cn);   // e^{2*cn}
    h = (ec - 1.f) * rcp_pair((eo + 1.f) * (ec + 1.f));
}

// Per-wave-tile LSTM state: 32 batch cols, this lane owns 4 units of col n.
struct Tile {
    f32x2 c01, c23;   // cell state, units (0,1)/(2,3) of this lane's half
    f32x2 h01, h23;   // hidden state
    uint_t pk0, pk1;  // h packed to f16 pairs for the next B fragment
};

__device__ __forceinline__ floatx16 gate_mfma(half8 A, uint_t xpk, const Tile& T,
                                              const floatx16& zacc) {
    uint4 bu;
    bu.x = xpk;               // k0,1  | k8,9   : x0, x1
    bu.y = T.pk0;             // k2,3  | k10,11 : h0,h1 | h4,h5
    bu.z = T.pk1;             // k4,5  | k12,13 : h2,h3 | h6,h7
    bu.w = 0x00003C00u;       // k6,7  | k14,15 : 1.0, 0 (bias slot)
    half8 B = __builtin_bit_cast(half8, bu);
    return __builtin_amdgcn_mfma_f32_32x32x16_f16(A, B, zacc, 0, 0, 0);
}

__device__ __forceinline__ void act_tile(const floatx16& d, Tile& T) {
    // D rows for this lane: reg j -> i-unit j, 4+j -> f, 8+j -> g, 12+j -> o
    f32x2 gi, gf, gg, go;
    gi.x = d[0];  gi.y = d[1];
    gf.x = d[4];  gf.y = d[5];
    gg.x = d[8];  gg.y = d[9];
    go.x = d[12]; go.y = d[13];
    act_pair(gi, gf, gg, go, T.c01, T.h01);
    gi.x = d[2];  gi.y = d[3];
    gf.x = d[6];  gf.y = d[7];
    gg.x = d[10]; gg.y = d[11];
    go.x = d[14]; go.y = d[15];
    act_pair(gi, gf, gg, go, T.c23, T.h23);

    T.pk0 = upk(T.h01.x, T.h01.y);
    T.pk1 = upk(T.h23.x, T.h23.y);
}

// One LSTM step for BOTH tiles: issue the two MFMAs back-to-back, THEN run
// both activation blocks. Tile B's MFMA latency hides under tile A's
// activation chain by construction (not by scheduler luck), and the act
// scheduler gets 4 independent f32x2 chains to interleave.
__device__ __forceinline__ void lstm_step2(half8 A, uint_t xpkA, uint_t xpkB,
                                           Tile& TA, Tile& TB,
                                           const floatx16& zacc) {
    floatx16 dA = gate_mfma(A, xpkA, TA, zacc);
    floatx16 dB = gate_mfma(A, xpkB, TB, zacc);
    act_tile(dA, TA);
    act_tile(dB, TB);
}

// ---------------------------------------------------------------------------
// Best measured config (R2): 4 waves/block x 2 tiles/wave, 2048 blocks,
// bounds(256,4). R4 (reg-squeezed) and R5 (ILP x4, grid 1024) both regressed;
// wall tracks ISSUE count + ~230cyc structural stall, so this round pairs the
// winning config with the 24-trans math + explicit MFMA/act stagger.
// ---------------------------------------------------------------------------
__global__ __launch_bounds__(256, 4)
void lstm_encoder(const float2* __restrict__ obs,
                  const float2* __restrict__ pre,
                  const float4* __restrict__ h0,
                  const float4* __restrict__ c0,
                  const float4* __restrict__ c0p,
                  const uint4* __restrict__ wf,
                  float* __restrict__ out) {
    const int tid  = threadIdx.x;
    const int lane = tid & 63;
    const int wv   = tid >> 6;              // wave in block: 0..3
    const int n    = lane & 31;             // batch col within tile
    const int half = lane >> 5;             // 0: units 0-3, 1: units 4-7
    const size_t nbA = (size_t)blockIdx.x * 256 + wv * 64 + n;
    const size_t nbB = nbA + 32;

    half8 Aobs = __builtin_bit_cast(half8, wf[lane]);
    half8 Apre = __builtin_bit_cast(half8, wf[64 + lane]);

    floatx16 zacc;
    #pragma unroll
    for (int i = 0; i < 16; i++) zacc[i] = 0.f;

    Tile TA, TB;
    {
        float4 hvA = h0[nbA * 2 + half];
        float4 cvA = c0[nbA * 2 + half];
        float4 hvB = h0[nbB * 2 + half];
        float4 cvB = c0[nbB * 2 + half];
        TA.c01.x = cvA.x; TA.c01.y = cvA.y; TA.c23.x = cvA.z; TA.c23.y = cvA.w;
        TB.c01.x = cvB.x; TB.c01.y = cvB.y; TB.c23.x = cvB.z; TB.c23.y = cvB.w;
        TA.pk0 = upk(hvA.x, hvA.y); TA.pk1 = upk(hvA.z, hvA.w);
        TB.pk0 = upk(hvB.x, hvB.y); TB.pk1 = upk(hvB.z, hvB.w);
    }
    // hoist c0_pre loads: latency hides under the whole obs phase
    float4 cvA2 = c0p[nbA * 2 + half];
    float4 cvB2 = c0p[nbB * 2 + half];

    // 1-deep x prefetch: next step's loads issue before this step's math.
    float2 xvA = obs[nbA];
    float2 xvB = obs[nbB];
    #pragma unroll 1
    for (int t = 0; t < T_OBS - 1; t++) {
        float2 xnA = obs[(size_t)(t + 1) * BATCH + nbA];
        float2 xnB = obs[(size_t)(t + 1) * BATCH + nbB];
        lstm_step2(Aobs, upk(xvA.x, xvA.y), upk(xvB.x, xvB.y), TA, TB, zacc);
        xvA = xnA; xvB = xnB;
    }
    {   // last obs step; prefetch first pre step
        float2 xnA = pre[nbA];
        float2 xnB = pre[nbB];
        lstm_step2(Aobs, upk(xvA.x, xvA.y), upk(xvB.x, xvB.y), TA, TB, zacc);
        xvA = xnA; xvB = xnB;
    }

    // c_out (transpose-then-reshape): out[u*B + b] = h[b][u]
    out[(size_t)(half * 4 + 0) * BATCH + nbA] = TA.h01.x;
    out[(size_t)(half * 4 + 1) * BATCH + nbA] = TA.h01.y;
    out[(size_t)(half * 4 + 2) * BATCH + nbA] = TA.h23.x;
    out[(size_t)(half * 4 + 3) * BATCH + nbA] = TA.h23.y;
    out[(size_t)(half * 4 + 0) * BATCH + nbB] = TB.h01.x;
    out[(size_t)(half * 4 + 1) * BATCH + nbB] = TB.h01.y;
    out[(size_t)(half * 4 + 2) * BATCH + nbB] = TB.h23.x;
    out[(size_t)(half * 4 + 3) * BATCH + nbB] = TB.h23.y;

    // pre phase: h carries over, c re-initialized
    TA.c01.x = cvA2.x; TA.c01.y = cvA2.y; TA.c23.x = cvA2.z; TA.c23.y = cvA2.w;
    TB.c01.x = cvB2.x; TB.c01.y = cvB2.y; TB.c23.x = cvB2.z; TB.c23.y = cvB2.w;

    #pragma unroll 1
    for (int t = 0; t < T_PRE - 1; t++) {
        float2 xnA = pre[(size_t)(t + 1) * BATCH + nbA];
        float2 xnB = pre[(size_t)(t + 1) * BATCH + nbB];
        lstm_step2(Apre, upk(xvA.x, xvA.y), upk(xvB.x, xvB.y), TA, TB, zacc);
        xvA = xnA; xvB = xnB;
    }
    lstm_step2(Apre, upk(xvA.x, xvA.y), upk(xvB.x, xvB.y), TA, TB, zacc);

    out[(size_t)(8 + half * 4 + 0) * BATCH + nbA] = TA.h01.x;
    out[(size_t)(8 + half * 4 + 1) * BATCH + nbA] = TA.h01.y;
    out[(size_t)(8 + half * 4 + 2) * BATCH + nbA] = TA.h23.x;
    out[(size_t)(8 + half * 4 + 3) * BATCH + nbA] = TA.h23.y;
    out[(size_t)(8 + half * 4 + 0) * BATCH + nbB] = TB.h01.x;
    out[(size_t)(8 + half * 4 + 1) * BATCH + nbB] = TB.h01.y;
    out[(size_t)(8 + half * 4 + 2) * BATCH + nbB] = TB.h23.x;
    out[(size_t)(8 + half * 4 + 3) * BATCH + nbB] = TB.h23.y;
}

extern "C" void kernel_launch(void* const* d_in, const int* in_sizes, int n_in,
                              void* d_out, int out_size, void* d_ws, size_t ws_size,
                              hipStream_t stream) {
    prep_weights<<<1, 128, 0, stream>>>(
        (const float*)d_in[5],  (const float*)d_in[6],
        (const float*)d_in[7],  (const float*)d_in[8],
        (const float*)d_in[9],  (const float*)d_in[10],
        (const float*)d_in[11], (const float*)d_in[12],
        (const float*)d_in[13], (const float*)d_in[14],
        (uint_t*)d_ws);

    lstm_encoder<<<BATCH / 256, 256, 0, stream>>>(
        (const float2*)d_in[0], (const float2*)d_in[1],
        (const float4*)d_in[2], (const float4*)d_in[3], (const float4*)d_in[4],
        (const uint4*)d_ws, (float*)d_out);
}

// Round 7
// 207.141 us; speedup vs baseline: 1.0422x; 1.0177x over previous
//
#include <hip/hip_runtime.h>
#include <stdint.h>

// Problem constants: T_OBS=8, T_PRE=12, B=524288, IN=2, E=16, H=8
#define T_OBS 8
#define T_PRE 12
#define BATCH 524288

#define NLOG2E  (-1.4426950408889634f)   // -log2(e): sigmoid prescale
#define P2LOG2E ( 2.8853900817779268f)   // +2*log2(e): tanh prescale

typedef __fp16 half8  __attribute__((ext_vector_type(8)));
typedef float  floatx16 __attribute__((ext_vector_type(16)));
typedef float  f32x2   __attribute__((ext_vector_type(2)));
typedef unsigned int uint_t;

__device__ __forceinline__ uint_t upk(float a, float b) {
    return __builtin_bit_cast(uint_t, __builtin_amdgcn_cvt_pkrtz(a, b));
}

// ---------------------------------------------------------------------------
// Weight prep -> per-lane MFMA A-fragments for v_mfma_f32_32x32x16_f16.
// A matrix: [M=32 gate rows (i0-7,f0-7,g0-7,o0-7)] x [K=16].
// SYMMETRIC half-lane layout (no cross-lane exchange needed in the step):
//   lower half supplies k0..7  = (x0, x1, h0, h1, h2, h3, 1, 0)
//   upper half supplies k8..15 = (x0, x1, h4, h5, h6, h7, 1, 0)
// A rows: k0,1/k8,9 = folded (W_ih@W_in)*0.5 ; k2..5/k10..13 = W_hh cols ;
//         k6/k14 = folded bias*0.5 ; k7/k15 = 0.
// Sigmoid rows (i,f,o) scaled by -log2e; tanh rows (g) by +2log2e.
// A-fragment layout: lane l holds A[m=l&31][k=(l>>5)*8 + j], j=0..7,
// packed as 4 dwords (f16 pairs). ws layout: uint[phase*256 + lane*4 + r].
// ---------------------------------------------------------------------------
__global__ void prep_weights(const float* __restrict__ W_in,
                             const float* __restrict__ b_in,
                             const float* __restrict__ W_ih_obs,
                             const float* __restrict__ W_hh_obs,
                             const float* __restrict__ b_ih_obs,
                             const float* __restrict__ b_hh_obs,
                             const float* __restrict__ W_ih_pre,
                             const float* __restrict__ W_hh_pre,
                             const float* __restrict__ b_ih_pre,
                             const float* __restrict__ b_hh_pre,
                             uint_t* __restrict__ wsu) {
    int t = threadIdx.x;            // 0..127: phase*64 + lane
    int phase = t >> 6;
    int l = t & 63;
    int m = l & 31;                 // gate row
    int kh = l >> 5;                // k-half: 0 -> k0..7, 1 -> k8..15
    const float* W_ih = phase ? W_ih_pre : W_ih_obs;
    const float* W_hh = phase ? W_hh_pre : W_hh_obs;
    const float* b_ih = phase ? b_ih_pre : b_ih_obs;
    const float* b_hh = phase ? b_hh_pre : b_hh_obs;

    float wx0 = 0.f, wx1 = 0.f;
    float bb = b_ih[m] + b_hh[m];
    #pragma unroll
    for (int e = 0; e < 16; e++) {
        float wie = W_ih[m * 16 + e];
        wx0 += wie * W_in[e * 2 + 0];
        wx1 += wie * W_in[e * 2 + 1];
        bb  += wie * b_in[e];
    }
    float s = (m >= 16 && m < 24) ? P2LOG2E : NLOG2E;

    float af[16];
    af[0] = wx0 * s * 0.5f;          // x slots appear in BOTH k-halves:
    af[1] = wx1 * s * 0.5f;          // half weight each (exact in f16)
    #pragma unroll
    for (int j = 0; j < 4; j++) af[2 + j] = W_hh[m * 8 + j] * s;
    af[6] = bb * s * 0.5f;
    af[7] = 0.f;
    af[8] = af[0];
    af[9] = af[1];
    #pragma unroll
    for (int j = 0; j < 4; j++) af[10 + j] = W_hh[m * 8 + 4 + j] * s;
    af[14] = af[6];
    af[15] = 0.f;

    #pragma unroll
    for (int r = 0; r < 4; r++)
        wsu[phase * 256 + l * 4 + r] = upk(af[kh * 8 + 2 * r], af[kh * 8 + 2 * r + 1]);
}

// ---------------------------------------------------------------------------
// Activation math on unit-PAIRS as <2 x float> so clang lowers the full-rate
// ops to v_pk_{add,mul,fma}_f32. Trans ops per unit: 5 exp2 + 1 shared rcp
// (paired Montgomery inversion: rcp(d0*d1) then two muls recovers 1/d0, 1/d1
// at ~2ulp — far below the f16-weight noise floor).
//   cn = [c*(1+ei)(1+eg) + (eg-1)(1+ef)] / [(1+ei)(1+ef)(1+eg)]
//   h  = (ec-1) / [(1+eo)(1+ec)],  ec = exp2(2*log2e*cn)
// Trans per tile-step: 16 gate exp2 + 4 tanh exp2 + 4 rcp = 24.
// ---------------------------------------------------------------------------
__device__ __forceinline__ f32x2 exp2v(f32x2 a) {
    f32x2 r;
    r.x = __builtin_amdgcn_exp2f(a.x);
    r.y = __builtin_amdgcn_exp2f(a.y);
    return r;
}
// 1/d.x, 1/d.y with a single v_rcp via batch inversion.
__device__ __forceinline__ f32x2 rcp_pair(f32x2 d) {
    float r = __builtin_amdgcn_rcpf(d.x * d.y);
    f32x2 o;
    o.x = r * d.y;
    o.y = r * d.x;
    return o;
}

__device__ __forceinline__ void act_pair(f32x2 gi, f32x2 gf, f32x2 gg, f32x2 go,
                                         f32x2& c, f32x2& h) {
    f32x2 ei = exp2v(gi);             // e^{-i}
    f32x2 ef = exp2v(gf);             // e^{-f}
    f32x2 eg = exp2v(gg);             // e^{2g}
    f32x2 eo = exp2v(go);             // e^{-o}
    f32x2 ai = ei + 1.f;
    f32x2 af = ef + 1.f;
    f32x2 ag = eg + 1.f;
    f32x2 gm = eg - 1.f;
    f32x2 p  = ai * ag;
    f32x2 num = c * p + gm * af;
    f32x2 cn  = num * rcp_pair(p * af);
    c = cn;
    f32x2 ec = exp2v(P2LOG2E * cn);   // e^{2*cn}
    h = (ec - 1.f) * rcp_pair((eo + 1.f) * (ec + 1.f));
}

// Per-wave-tile LSTM state: 32 batch cols, this lane owns 4 units of col n.
struct Tile {
    f32x2 c01, c23;   // cell state, units (0,1)/(2,3) of this lane's half
    f32x2 h01, h23;   // hidden state
    uint_t pk0, pk1;  // h packed to f16 pairs for the next B fragment
};

__device__ __forceinline__ floatx16 gate_mfma(half8 A, uint_t xpk, const Tile& T,
                                              const floatx16& zacc) {
    uint4 bu;
    bu.x = xpk;               // k0,1  | k8,9   : x0, x1
    bu.y = T.pk0;             // k2,3  | k10,11 : h0,h1 | h4,h5
    bu.z = T.pk1;             // k4,5  | k12,13 : h2,h3 | h6,h7
    bu.w = 0x00003C00u;       // k6,7  | k14,15 : 1.0, 0 (bias slot)
    half8 B = __builtin_bit_cast(half8, bu);
    return __builtin_amdgcn_mfma_f32_32x32x16_f16(A, B, zacc, 0, 0, 0);
}

__device__ __forceinline__ void act_tile(const floatx16& d, Tile& T) {
    // D rows for this lane: reg j -> i-unit j, 4+j -> f, 8+j -> g, 12+j -> o
    f32x2 gi, gf, gg, go;
    gi.x = d[0];  gi.y = d[1];
    gf.x = d[4];  gf.y = d[5];
    gg.x = d[8];  gg.y = d[9];
    go.x = d[12]; go.y = d[13];
    act_pair(gi, gf, gg, go, T.c01, T.h01);
    gi.x = d[2];  gi.y = d[3];
    gf.x = d[6];  gf.y = d[7];
    gg.x = d[10]; gg.y = d[11];
    go.x = d[14]; go.y = d[15];
    act_pair(gi, gf, gg, go, T.c23, T.h23);

    T.pk0 = upk(T.h01.x, T.h01.y);
    T.pk1 = upk(T.h23.x, T.h23.y);
}

// One LSTM step for BOTH tiles: both MFMAs issue back-to-back, then both
// activation blocks (tile B's MFMA latency hides under tile A's act chain).
__device__ __forceinline__ void lstm_step2(half8 A, uint_t xpkA, uint_t xpkB,
                                           Tile& TA, Tile& TB,
                                           const floatx16& zacc) {
    floatx16 dA = gate_mfma(A, xpkA, TA, zacc);
    floatx16 dB = gate_mfma(A, xpkB, TB, zacc);
    act_tile(dA, TA);
    act_tile(dB, TB);
}

// ---------------------------------------------------------------------------
// R2's winning config (2048x256, 2 tiles/wave, bounds(256,4)) + FULL x-stream
// register hoist. Diagnosis across R1-R6: wall/tile-step pinned at ~592-601cyc
// with ~215cyc idle regardless of occupancy/ILP/stagger => the idle is the
// per-step float2 load whose 1-deep prefetch (~590cyc lead) doesn't cover
// L2/LLC/HBM latency, and lockstep waves stall together. T_OBS/T_PRE are
// compile-time: issue ALL 20 loads per tile at kernel start into registers
// (static indices -> no scratch, rule #20) and fully unroll both time loops.
// Zero loads inside the compute stream; one prologue vmcnt drain total.
// ---------------------------------------------------------------------------
__global__ __launch_bounds__(256, 4)
void lstm_encoder(const float2* __restrict__ obs,
                  const float2* __restrict__ pre,
                  const float4* __restrict__ h0,
                  const float4* __restrict__ c0,
                  const float4* __restrict__ c0p,
                  const uint4* __restrict__ wf,
                  float* __restrict__ out) {
    const int tid  = threadIdx.x;
    const int lane = tid & 63;
    const int wv   = tid >> 6;              // wave in block: 0..3
    const int n    = lane & 31;             // batch col within tile
    const int half = lane >> 5;             // 0: units 0-3, 1: units 4-7
    const size_t nbA = (size_t)blockIdx.x * 256 + wv * 64 + n;
    const size_t nbB = nbA + 32;

    half8 Aobs = __builtin_bit_cast(half8, wf[lane]);
    half8 Apre = __builtin_bit_cast(half8, wf[64 + lane]);

    floatx16 zacc;
    #pragma unroll
    for (int i = 0; i < 16; i++) zacc[i] = 0.f;

    // ---- hoist the ENTIRE x stream into registers (static indices) ----
    float2 xoA[T_OBS], xoB[T_OBS], xpA[T_PRE], xpB[T_PRE];
    #pragma unroll
    for (int t = 0; t < T_OBS; t++) {
        xoA[t] = obs[(size_t)t * BATCH + nbA];
        xoB[t] = obs[(size_t)t * BATCH + nbB];
    }
    #pragma unroll
    for (int t = 0; t < T_PRE; t++) {
        xpA[t] = pre[(size_t)t * BATCH + nbA];
        xpB[t] = pre[(size_t)t * BATCH + nbB];
    }

    Tile TA, TB;
    {
        float4 hvA = h0[nbA * 2 + half];
        float4 cvA = c0[nbA * 2 + half];
        float4 hvB = h0[nbB * 2 + half];
        float4 cvB = c0[nbB * 2 + half];
        TA.c01.x = cvA.x; TA.c01.y = cvA.y; TA.c23.x = cvA.z; TA.c23.y = cvA.w;
        TB.c01.x = cvB.x; TB.c01.y = cvB.y; TB.c23.x = cvB.z; TB.c23.y = cvB.w;
        TA.pk0 = upk(hvA.x, hvA.y); TA.pk1 = upk(hvA.z, hvA.w);
        TB.pk0 = upk(hvB.x, hvB.y); TB.pk1 = upk(hvB.z, hvB.w);
    }
    // hoist c0_pre loads: latency hides under the whole obs phase
    float4 cvA2 = c0p[nbA * 2 + half];
    float4 cvB2 = c0p[nbB * 2 + half];

    #pragma unroll
    for (int t = 0; t < T_OBS; t++)
        lstm_step2(Aobs, upk(xoA[t].x, xoA[t].y), upk(xoB[t].x, xoB[t].y),
                   TA, TB, zacc);

    // c_out (transpose-then-reshape): out[u*B + b] = h[b][u]
    out[(size_t)(half * 4 + 0) * BATCH + nbA] = TA.h01.x;
    out[(size_t)(half * 4 + 1) * BATCH + nbA] = TA.h01.y;
    out[(size_t)(half * 4 + 2) * BATCH + nbA] = TA.h23.x;
    out[(size_t)(half * 4 + 3) * BATCH + nbA] = TA.h23.y;
    out[(size_t)(half * 4 + 0) * BATCH + nbB] = TB.h01.x;
    out[(size_t)(half * 4 + 1) * BATCH + nbB] = TB.h01.y;
    out[(size_t)(half * 4 + 2) * BATCH + nbB] = TB.h23.x;
    out[(size_t)(half * 4 + 3) * BATCH + nbB] = TB.h23.y;

    // pre phase: h carries over, c re-initialized
    TA.c01.x = cvA2.x; TA.c01.y = cvA2.y; TA.c23.x = cvA2.z; TA.c23.y = cvA2.w;
    TB.c01.x = cvB2.x; TB.c01.y = cvB2.y; TB.c23.x = cvB2.z; TB.c23.y = cvB2.w;

    #pragma unroll
    for (int t = 0; t < T_PRE; t++)
        lstm_step2(Apre, upk(xpA[t].x, xpA[t].y), upk(xpB[t].x, xpB[t].y),
                   TA, TB, zacc);

    out[(size_t)(8 + half * 4 + 0) * BATCH + nbA] = TA.h01.x;
    out[(size_t)(8 + half * 4 + 1) * BATCH + nbA] = TA.h01.y;
    out[(size_t)(8 + half * 4 + 2) * BATCH + nbA] = TA.h23.x;
    out[(size_t)(8 + half * 4 + 3) * BATCH + nbA] = TA.h23.y;
    out[(size_t)(8 + half * 4 + 0) * BATCH + nbB] = TB.h01.x;
    out[(size_t)(8 + half * 4 + 1) * BATCH + nbB] = TB.h01.y;
    out[(size_t)(8 + half * 4 + 2) * BATCH + nbB] = TB.h23.x;
    out[(size_t)(8 + half * 4 + 3) * BATCH + nbB] = TB.h23.y;
}

extern "C" void kernel_launch(void* const* d_in, const int* in_sizes, int n_in,
                              void* d_out, int out_size, void* d_ws, size_t ws_size,
                              hipStream_t stream) {
    prep_weights<<<1, 128, 0, stream>>>(
        (const float*)d_in[5],  (const float*)d_in[6],
        (const float*)d_in[7],  (const float*)d_in[8],
        (const float*)d_in[9],  (const float*)d_in[10],
        (const float*)d_in[11], (const float*)d_in[12],
        (const float*)d_in[13], (const float*)d_in[14],
        (uint_t*)d_ws);

    lstm_encoder<<<BATCH / 256, 256, 0, stream>>>(
        (const float2*)d_in[0], (const float2*)d_in[1],
        (const float4*)d_in[2], (const float4*)d_in[3], (const float4*)d_in[4],
        (const uint4*)d_ws, (float*)d_out);
}